// Round 1
// baseline (735.450 us; speedup 1.0000x reference)
//
#include <hip/hip_runtime.h>
#include <hip/hip_bf16.h>
#include <cstdint>
#include <cstddef>

#define T_TOK 4096
#define DIM   1024
#define IDIM  1024
#define NEXP  32
#define TOPK  4

#define BM 64
#define BN 64
#define BK 64
#define LDSP 72   // 64 + 8 bf16 pad: breaks 16-way bank conflict on ds_read_b128, keeps 16B align

typedef short bf16x8 __attribute__((ext_vector_type(8)));
typedef float f32x4  __attribute__((ext_vector_type(4)));

__device__ __forceinline__ short bf(float f) {
    union { float f; uint32_t u; } v; v.f = f;
    uint32_t r = (v.u + 0x7FFFu + ((v.u >> 16) & 1u)) >> 16;   // RNE
    return (short)r;
}

// ---------------- Router: one wave per token, fp32 ----------------
__global__ __launch_bounds__(256) void router_kernel(
    const float* __restrict__ X, const float* __restrict__ GW,
    const float* __restrict__ bias, int* __restrict__ topk_idx,
    float* __restrict__ topk_w)
{
    int wid  = threadIdx.x >> 6;
    int lane = threadIdx.x & 63;
    int t = blockIdx.x * 4 + wid;

    float4 h[4];
    const float4* xr = reinterpret_cast<const float4*>(X + (size_t)t * DIM);
    #pragma unroll
    for (int c = 0; c < 4; ++c) h[c] = xr[lane + 64 * c];

    float myscore = 0.f;  // logit for expert == lane (lanes 0..31)
    for (int e = 0; e < NEXP; ++e) {
        const float4* gr = reinterpret_cast<const float4*>(GW + (size_t)e * DIM);
        float p = 0.f;
        #pragma unroll
        for (int c = 0; c < 4; ++c) {
            float4 g = gr[lane + 64 * c];
            p += h[c].x * g.x + h[c].y * g.y + h[c].z * g.z + h[c].w * g.w;
        }
        #pragma unroll
        for (int o = 32; o; o >>= 1) p += __shfl_xor(p, o);
        if (lane == e) myscore = p;
    }
    float rw = 1.f / (1.f + expf(-myscore));           // routing weight (no bias)
    float sel = (lane < NEXP) ? rw + bias[lane] : -1e30f;  // selection score (+bias)

    float wsum = 0.f;
    int   oi = 0; float ow = 0.f;
    #pragma unroll
    for (int k = 0; k < TOPK; ++k) {
        float v = sel;
        int   idx = (lane < NEXP) ? lane : 9999;
        #pragma unroll
        for (int o = 32; o; o >>= 1) {           // argmax, tie -> lowest index (lax.top_k)
            float v2 = __shfl_xor(v, o);
            int   i2 = __shfl_xor(idx, o);
            if (v2 > v || (v2 == v && i2 < idx)) { v = v2; idx = i2; }
        }
        float wk = __shfl(rw, idx);
        wsum += wk;
        if (lane == k)   { oi = idx; ow = wk; }
        if (lane == idx) sel = -1e30f;
    }
    if (lane < TOPK) {
        topk_idx[t * TOPK + lane] = oi;
        topk_w  [t * TOPK + lane] = ow / (wsum + 1e-6f);
    }
}

// ---------------- Scatter into per-expert lists ----------------
__global__ void scatter_kernel(const int* __restrict__ topk_idx,
                               const float* __restrict__ topk_w,
                               int* __restrict__ cnt,
                               int* __restrict__ tlist,
                               float* __restrict__ wlist)
{
    int gid = blockIdx.x * blockDim.x + threadIdx.x;
    if (gid >= T_TOK * TOPK) return;
    int e = topk_idx[gid];
    int pos = atomicAdd(&cnt[e], 1);
    tlist[e * T_TOK + pos] = gid >> 2;       // token id
    wlist[e * T_TOK + pos] = topk_w[gid];
}

__global__ void prefix_kernel(const int* __restrict__ cnt, int* __restrict__ offs)
{
    if (threadIdx.x == 0) {
        int acc = 0;
        for (int e = 0; e < NEXP; ++e) { offs[e] = acc; acc += cnt[e]; }
        offs[NEXP] = acc;
    }
}

// ---------------- GEMM1: X @ Wgu^T (g and u tiles), silu fuse, H bf16 ----------------
__global__ __launch_bounds__(256) void gemm1_kernel(
    const float* __restrict__ X, const float* __restrict__ GUP,
    const int* __restrict__ cnt, const int* __restrict__ offs,
    const int* __restrict__ tlist, short* __restrict__ H)
{
    const int NT = IDIM / BN;     // 16
    const int MT = T_TOK / BM;    // 64 (worst case)
    int bid = blockIdx.x;
    int e   = bid / (MT * NT);
    int rem = bid % (MT * NT);
    int mt  = rem / NT;
    int nt  = rem % NT;
    int count = cnt[e];
    int m0 = mt * BM;
    if (m0 >= count) return;
    int n0 = nt * BN;

    __shared__ short As[BM][LDSP];
    __shared__ short Bg[BN][LDSP];
    __shared__ short Bu[BN][LDSP];

    int tid = threadIdx.x, lane = tid & 63, wid = tid >> 6;
    int wm = (wid >> 1) * 32, wn = (wid & 1) * 32;

    int ar  = tid >> 2;
    int akb = (tid & 3) * 16;
    int tok = -1;
    if (m0 + ar < count) tok = tlist[e * T_TOK + m0 + ar];
    const float* xrow = X + (size_t)(tok < 0 ? 0 : tok) * DIM;
    const float* grow = GUP + ((size_t)e * 2 * IDIM + n0 + ar) * DIM;
    const float* urow = GUP + ((size_t)e * 2 * IDIM + IDIM + n0 + ar) * DIM;

    f32x4 accg[2][2] = {};
    f32x4 accu[2][2] = {};

    for (int k0 = 0; k0 < DIM; k0 += BK) {
        #pragma unroll
        for (int j = 0; j < 4; ++j) {
            int kk = akb + j * 4;
            float4 av = make_float4(0.f, 0.f, 0.f, 0.f);
            if (tok >= 0) av = *reinterpret_cast<const float4*>(xrow + k0 + kk);
            float4 gv = *reinterpret_cast<const float4*>(grow + k0 + kk);
            float4 uv = *reinterpret_cast<const float4*>(urow + k0 + kk);
            *reinterpret_cast<short4*>(&As[ar][kk]) = make_short4(bf(av.x), bf(av.y), bf(av.z), bf(av.w));
            *reinterpret_cast<short4*>(&Bg[ar][kk]) = make_short4(bf(gv.x), bf(gv.y), bf(gv.z), bf(gv.w));
            *reinterpret_cast<short4*>(&Bu[ar][kk]) = make_short4(bf(uv.x), bf(uv.y), bf(uv.z), bf(uv.w));
        }
        __syncthreads();
        #pragma unroll
        for (int kk = 0; kk < BK; kk += 32) {
            int krd = kk + (lane >> 4) * 8;
            bf16x8 af[2], gf[2], uf[2];
            #pragma unroll
            for (int fm = 0; fm < 2; ++fm)
                af[fm] = *reinterpret_cast<const bf16x8*>(&As[wm + fm * 16 + (lane & 15)][krd]);
            #pragma unroll
            for (int fn = 0; fn < 2; ++fn) {
                gf[fn] = *reinterpret_cast<const bf16x8*>(&Bg[wn + fn * 16 + (lane & 15)][krd]);
                uf[fn] = *reinterpret_cast<const bf16x8*>(&Bu[wn + fn * 16 + (lane & 15)][krd]);
            }
            #pragma unroll
            for (int fm = 0; fm < 2; ++fm)
                #pragma unroll
                for (int fn = 0; fn < 2; ++fn) {
                    accg[fm][fn] = __builtin_amdgcn_mfma_f32_16x16x32_bf16(af[fm], gf[fn], accg[fm][fn], 0, 0, 0);
                    accu[fm][fn] = __builtin_amdgcn_mfma_f32_16x16x32_bf16(af[fm], uf[fn], accu[fm][fn], 0, 0, 0);
                }
        }
        __syncthreads();
    }

    int off_e = offs[e];
    #pragma unroll
    for (int fm = 0; fm < 2; ++fm) {
        #pragma unroll
        for (int r = 0; r < 4; ++r) {
            int lrow = wm + fm * 16 + (lane >> 4) * 4 + r;
            if (m0 + lrow >= count) continue;
            size_t hbase = (size_t)(off_e + m0 + lrow) * IDIM;
            #pragma unroll
            for (int fn = 0; fn < 2; ++fn) {
                int col = n0 + wn + fn * 16 + (lane & 15);
                float g = accg[fm][fn][r];
                float u = accu[fm][fn][r];
                float hval = g / (1.f + expf(-g)) * u;   // silu(g)*u
                H[hbase + col] = bf(hval);
            }
        }
    }
}

// ---------------- GEMM2: H @ Wd^T, scale by routing weight, atomicAdd out ----------------
__global__ __launch_bounds__(256) void gemm2_kernel(
    const short* __restrict__ H, const float* __restrict__ DP,
    const int* __restrict__ cnt, const int* __restrict__ offs,
    const int* __restrict__ tlist, const float* __restrict__ wlist,
    float* __restrict__ out)
{
    const int NT = DIM / BN;      // 16
    const int MT = T_TOK / BM;    // 64
    int bid = blockIdx.x;
    int e   = bid / (MT * NT);
    int rem = bid % (MT * NT);
    int mt  = rem / NT;
    int nt  = rem % NT;
    int count = cnt[e];
    int m0 = mt * BM;
    if (m0 >= count) return;
    int n0 = nt * BN;

    __shared__ short As[BM][LDSP];
    __shared__ short Bd[BN][LDSP];

    int tid = threadIdx.x, lane = tid & 63, wid = tid >> 6;
    int wm = (wid >> 1) * 32, wn = (wid & 1) * 32;
    int off_e = offs[e];

    int ar  = tid >> 2;
    int akb = (tid & 3) * 16;
    bool arow_ok = (m0 + ar < count);
    const short* hrow = H + (size_t)(off_e + m0 + ar) * IDIM;
    const float* drow = DP + ((size_t)e * DIM + n0 + ar) * IDIM;

    f32x4 acc[2][2] = {};

    for (int k0 = 0; k0 < IDIM; k0 += BK) {
        if (arow_ok) {
            *reinterpret_cast<int4*>(&As[ar][akb])     = *reinterpret_cast<const int4*>(hrow + k0 + akb);
            *reinterpret_cast<int4*>(&As[ar][akb + 8]) = *reinterpret_cast<const int4*>(hrow + k0 + akb + 8);
        } else {
            *reinterpret_cast<int4*>(&As[ar][akb])     = make_int4(0, 0, 0, 0);
            *reinterpret_cast<int4*>(&As[ar][akb + 8]) = make_int4(0, 0, 0, 0);
        }
        #pragma unroll
        for (int j = 0; j < 4; ++j) {
            int kk = akb + j * 4;
            float4 dv = *reinterpret_cast<const float4*>(drow + k0 + kk);
            *reinterpret_cast<short4*>(&Bd[ar][kk]) = make_short4(bf(dv.x), bf(dv.y), bf(dv.z), bf(dv.w));
        }
        __syncthreads();
        #pragma unroll
        for (int kk = 0; kk < BK; kk += 32) {
            int krd = kk + (lane >> 4) * 8;
            bf16x8 af[2], df[2];
            #pragma unroll
            for (int fm = 0; fm < 2; ++fm)
                af[fm] = *reinterpret_cast<const bf16x8*>(&As[wm + fm * 16 + (lane & 15)][krd]);
            #pragma unroll
            for (int fn = 0; fn < 2; ++fn)
                df[fn] = *reinterpret_cast<const bf16x8*>(&Bd[wn + fn * 16 + (lane & 15)][krd]);
            #pragma unroll
            for (int fm = 0; fm < 2; ++fm)
                #pragma unroll
                for (int fn = 0; fn < 2; ++fn)
                    acc[fm][fn] = __builtin_amdgcn_mfma_f32_16x16x32_bf16(af[fm], df[fn], acc[fm][fn], 0, 0, 0);
        }
        __syncthreads();
    }

    #pragma unroll
    for (int fm = 0; fm < 2; ++fm) {
        #pragma unroll
        for (int r = 0; r < 4; ++r) {
            int lrow = wm + fm * 16 + (lane >> 4) * 4 + r;
            if (m0 + lrow >= count) continue;
            int t     = tlist[e * T_TOK + m0 + lrow];
            float wgt = wlist[e * T_TOK + m0 + lrow];
            #pragma unroll
            for (int fn = 0; fn < 2; ++fn) {
                int col = n0 + wn + fn * 16 + (lane & 15);
                atomicAdd(&out[(size_t)t * DIM + col], acc[fm][fn][r] * wgt);
            }
        }
    }
}

// ---------------- launch ----------------
extern "C" void kernel_launch(void* const* d_in, const int* in_sizes, int n_in,
                              void* d_out, int out_size, void* d_ws, size_t ws_size,
                              hipStream_t stream)
{
    const float* X    = (const float*)d_in[0];
    const float* GW   = (const float*)d_in[1];
    const float* GUP  = (const float*)d_in[2];
    const float* DP   = (const float*)d_in[3];
    const float* BIAS = (const float*)d_in[4];
    float* out = (float*)d_out;

    char* ws = (char*)d_ws;
    int*   cnt      = (int*)(ws + 0);
    int*   offs     = (int*)(ws + 256);
    int*   topk_idx = (int*)(ws + 1024);
    float* topk_w   = (float*)(ws + 1024 + 65536);
    int*   tlist    = (int*)(ws + 1024 + 131072);
    float* wlist    = (float*)(ws + 1024 + 131072 + 524288);
    short* H        = (short*)(ws + 1024 + 131072 + 1048576 + 1024);  // 32 MB bf16

    (void)hipMemsetAsync(cnt, 0, 256, stream);
    (void)hipMemsetAsync(d_out, 0, (size_t)T_TOK * DIM * sizeof(float), stream);

    router_kernel<<<T_TOK / 4, 256, 0, stream>>>(X, GW, BIAS, topk_idx, topk_w);
    scatter_kernel<<<(T_TOK * TOPK + 255) / 256, 256, 0, stream>>>(topk_idx, topk_w, cnt, tlist, wlist);
    prefix_kernel<<<1, 64, 0, stream>>>(cnt, offs);

    int blocks1 = NEXP * (T_TOK / BM) * (IDIM / BN);
    gemm1_kernel<<<blocks1, 256, 0, stream>>>(X, GUP, cnt, offs, tlist, H);
    int blocks2 = NEXP * (T_TOK / BM) * (DIM / BN);
    gemm2_kernel<<<blocks2, 256, 0, stream>>>(H, DP, cnt, offs, tlist, wlist, out);
}

// Round 2
// 590.943 us; speedup vs baseline: 1.2445x; 1.2445x over previous
//
#include <hip/hip_runtime.h>
#include <hip/hip_bf16.h>
#include <cstdint>
#include <cstddef>

#define T_TOK 4096
#define DIM   1024
#define IDIM  1024
#define NEXP  32
#define TOPK  4
#define MAXT  160            // max 128-row m-tiles: 16384/128 + 32
#define RPAD  (MAXT*128)     // 20480 padded rows max

typedef short sh8  __attribute__((ext_vector_type(8)));
typedef float f32x4 __attribute__((ext_vector_type(4)));

__device__ __forceinline__ short bf(float f) {
    union { float f; uint32_t u; } v; v.f = f;
    uint32_t r = (v.u + 0x7FFFu + ((v.u >> 16) & 1u)) >> 16;   // RNE
    return (short)r;
}
__device__ __forceinline__ sh8 pack8(float4 a, float4 b) {
    sh8 r;
    r[0]=bf(a.x); r[1]=bf(a.y); r[2]=bf(a.z); r[3]=bf(a.w);
    r[4]=bf(b.x); r[5]=bf(b.y); r[6]=bf(b.z); r[7]=bf(b.w);
    return r;
}
__device__ __forceinline__ void glds16(const void* g, const void* l) {
    __builtin_amdgcn_global_load_lds((const __attribute__((address_space(1))) void*)g,
                                     (__attribute__((address_space(3))) void*)l, 16, 0, 0);
}

// ---------------- Router: one wave per token, fp32 (verified round 1) ----------------
__global__ __launch_bounds__(256) void router_kernel(
    const float* __restrict__ X, const float* __restrict__ GW,
    const float* __restrict__ bias, int* __restrict__ topk_idx,
    float* __restrict__ topk_w)
{
    int wid  = threadIdx.x >> 6;
    int lane = threadIdx.x & 63;
    int t = blockIdx.x * 4 + wid;

    float4 h[4];
    const float4* xr = reinterpret_cast<const float4*>(X + (size_t)t * DIM);
    #pragma unroll
    for (int c = 0; c < 4; ++c) h[c] = xr[lane + 64 * c];

    float myscore = 0.f;
    for (int e = 0; e < NEXP; ++e) {
        const float4* gr = reinterpret_cast<const float4*>(GW + (size_t)e * DIM);
        float p = 0.f;
        #pragma unroll
        for (int c = 0; c < 4; ++c) {
            float4 g = gr[lane + 64 * c];
            p += h[c].x * g.x + h[c].y * g.y + h[c].z * g.z + h[c].w * g.w;
        }
        #pragma unroll
        for (int o = 32; o; o >>= 1) p += __shfl_xor(p, o);
        if (lane == e) myscore = p;
    }
    float rw = 1.f / (1.f + expf(-myscore));
    float sel = (lane < NEXP) ? rw + bias[lane] : -1e30f;

    float wsum = 0.f;
    int   oi = 0; float ow = 0.f;
    #pragma unroll
    for (int k = 0; k < TOPK; ++k) {
        float v = sel;
        int   idx = (lane < NEXP) ? lane : 9999;
        #pragma unroll
        for (int o = 32; o; o >>= 1) {
            float v2 = __shfl_xor(v, o);
            int   i2 = __shfl_xor(idx, o);
            if (v2 > v || (v2 == v && i2 < idx)) { v = v2; idx = i2; }
        }
        float wk = __shfl(rw, idx);
        wsum += wk;
        if (lane == k)   { oi = idx; ow = wk; }
        if (lane == idx) sel = -1e30f;
    }
    if (lane < TOPK) {
        topk_idx[t * TOPK + lane] = oi;
        topk_w  [t * TOPK + lane] = ow / (wsum + 1e-6f);
    }
}

// ---------------- Scatter into per-expert compact lists ----------------
__global__ void scatter_kernel(const int* __restrict__ topk_idx,
                               const float* __restrict__ topk_w,
                               int* __restrict__ cnt,
                               int* __restrict__ tlist_c,
                               float* __restrict__ wlist_c)
{
    int gid = blockIdx.x * blockDim.x + threadIdx.x;
    if (gid >= T_TOK * TOPK) return;
    int e = topk_idx[gid];
    int pos = atomicAdd(&cnt[e], 1);
    tlist_c[e * T_TOK + pos] = gid >> 2;
    wlist_c[e * T_TOK + pos] = topk_w[gid];
}

// ---------------- Plan: padded 128-aligned offsets + tile->expert map ----------------
// meta[0..32]=offs_p, meta[33]=ntiles, meta[34]=rows_pad, meta[64+t]=tile2e, meta[256+e]=cnt
__global__ void plan_kernel(int* __restrict__ meta)
{
    if (threadIdx.x == 0) {
        int acc = 0, t = 0;
        for (int e = 0; e < NEXP; ++e) {
            meta[e] = acc;
            int c = meta[256 + e];
            int ntl = (c + 127) >> 7;
            for (int i = 0; i < ntl; ++i) meta[64 + t++] = e;
            acc += ntl * 128;
        }
        meta[32] = acc;
        meta[33] = t;
        meta[34] = acc;
    }
}

// ---------------- Gather: build padded tlist/wlist (+ optional Xg bf16) ----------------
template<bool DO_XG>
__global__ __launch_bounds__(256) void gather_kernel(
    const float* __restrict__ X, const int* __restrict__ meta,
    const int* __restrict__ tlist_c, const float* __restrict__ wlist_c,
    short* __restrict__ Xg, int* __restrict__ tlist_p, float* __restrict__ wlist_p)
{
    int wid = threadIdx.x >> 6, lane = threadIdx.x & 63;
    int r = blockIdx.x * 4 + wid;
    if (r >= meta[34]) return;
    int e  = meta[64 + (r >> 7)];
    int li = r - meta[e];
    bool real = li < meta[256 + e];
    int t = 0; float w = 0.f;
    if (real) { t = tlist_c[e * T_TOK + li]; w = wlist_c[e * T_TOK + li]; }
    if (lane == 0) { tlist_p[r] = t; wlist_p[r] = w; }
    if (DO_XG) {
        const float4* src = reinterpret_cast<const float4*>(X + (size_t)t * DIM);
        sh8* dst = reinterpret_cast<sh8*>(Xg + (size_t)r * DIM);
        float4 z = make_float4(0.f, 0.f, 0.f, 0.f);
        #pragma unroll
        for (int it = 0; it < 2; ++it) {
            int si = it * 64 + lane;
            float4 a = real ? src[2 * si]     : z;
            float4 b = real ? src[2 * si + 1] : z;
            dst[si] = pack8(a, b);
        }
    }
}

// ---------------- Weight convert fp32 -> bf16 (tier1) ----------------
#define GUP_ELEMS 67108864ull   // 32*2048*1024
#define ALL_ELEMS 100663296ull  // + 32*1024*1024
__global__ __launch_bounds__(256) void convert_kernel(
    const float* __restrict__ gup, const float* __restrict__ dp,
    short* __restrict__ wgu, short* __restrict__ wd)
{
    size_t i = ((size_t)blockIdx.x * 256 + threadIdx.x) * 8;
    const float* src; short* dst;
    if (i < GUP_ELEMS) { src = gup + i; dst = wgu + i; }
    else               { src = dp + (i - GUP_ELEMS); dst = wd + (i - GUP_ELEMS); }
    float4 a = *reinterpret_cast<const float4*>(src);
    float4 b = *reinterpret_cast<const float4*>(src + 4);
    *reinterpret_cast<sh8*>(dst) = pack8(a, b);
}

// ---------------- GEMM1: Xg @ Wgu^T (g,u fused), silu, H bf16 ----------------
// tile: 128(M) x 64(N for each of g,u), BK=64. 4 waves, wave-tile 64x32 (x2 for g,u).
template<bool A_GLDS, bool W_BF16>
__global__ __launch_bounds__(256) void gemm1_kernel(
    const short* __restrict__ Xg, const float* __restrict__ X,
    const short* __restrict__ Wgu, const float* __restrict__ GUP,
    const int* __restrict__ meta, const int* __restrict__ tlist_p,
    short* __restrict__ H)
{
    int mt = blockIdx.x >> 4;
    int nt = blockIdx.x & 15;
    if (mt >= meta[33]) return;
    int e  = meta[64 + mt];
    int m0 = mt * 128, n0 = nt * 64;

    __shared__ short As[128 * 64];
    __shared__ short Bg[64 * 64];
    __shared__ short Bu[64 * 64];

    int tid = threadIdx.x, lane = tid & 63, wv = tid >> 6;
    int wm = (wv >> 1) * 64, wn = (wv & 1) * 32;

    f32x4 accg[4][2] = {};
    f32x4 accu[4][2] = {};

    // reg-staging geometry
    const float* xrow = nullptr; int arow = 0, acol = 0;
    if (!A_GLDS) {
        arow = tid >> 1; acol = (tid & 1) * 32;
        xrow = X + (size_t)tlist_p[m0 + arow] * DIM;
    }
    const float* grow = nullptr; const float* urow = nullptr;
    int brow = tid >> 2, bcol = (tid & 3) * 16;
    if (!W_BF16) {
        grow = GUP + ((size_t)e * 2 * IDIM + n0 + brow) * DIM;
        urow = GUP + ((size_t)e * 2 * IDIM + IDIM + n0 + brow) * DIM;
    }

    for (int k0 = 0; k0 < DIM; k0 += 64) {
        if (A_GLDS) {
            #pragma unroll
            for (int j = 0; j < 4; ++j) {
                int ch = wv * 4 + j;
                int rr = ch * 8 + (lane >> 3);
                glds16(Xg + (size_t)(m0 + rr) * DIM + k0 + (lane & 7) * 8, &As[ch * 512]);
            }
        } else {
            #pragma unroll
            for (int j = 0; j < 4; ++j) {
                float4 a = *reinterpret_cast<const float4*>(xrow + k0 + acol + j * 8);
                float4 b = *reinterpret_cast<const float4*>(xrow + k0 + acol + j * 8 + 4);
                *reinterpret_cast<sh8*>(&As[arow * 64 + acol + j * 8]) = pack8(a, b);
            }
        }
        if (W_BF16) {
            #pragma unroll
            for (int j = 0; j < 2; ++j) {
                int ch = wv * 2 + j;
                int rr = ch * 8 + (lane >> 3);
                glds16(Wgu + ((size_t)e * 2 * IDIM + n0 + rr) * DIM + k0 + (lane & 7) * 8, &Bg[ch * 512]);
                glds16(Wgu + ((size_t)e * 2 * IDIM + IDIM + n0 + rr) * DIM + k0 + (lane & 7) * 8, &Bu[ch * 512]);
            }
        } else {
            #pragma unroll
            for (int j = 0; j < 2; ++j) {
                float4 a = *reinterpret_cast<const float4*>(grow + k0 + bcol + j * 8);
                float4 b = *reinterpret_cast<const float4*>(grow + k0 + bcol + j * 8 + 4);
                *reinterpret_cast<sh8*>(&Bg[brow * 64 + bcol + j * 8]) = pack8(a, b);
                a = *reinterpret_cast<const float4*>(urow + k0 + bcol + j * 8);
                b = *reinterpret_cast<const float4*>(urow + k0 + bcol + j * 8 + 4);
                *reinterpret_cast<sh8*>(&Bu[brow * 64 + bcol + j * 8]) = pack8(a, b);
            }
        }
        __syncthreads();
        #pragma unroll
        for (int kk = 0; kk < 64; kk += 32) {
            int krd = kk + (lane >> 4) * 8;
            sh8 af[4], gf[2], uf[2];
            #pragma unroll
            for (int fm = 0; fm < 4; ++fm)
                af[fm] = *reinterpret_cast<const sh8*>(&As[(wm + fm * 16 + (lane & 15)) * 64 + krd]);
            #pragma unroll
            for (int fn = 0; fn < 2; ++fn) {
                gf[fn] = *reinterpret_cast<const sh8*>(&Bg[(wn + fn * 16 + (lane & 15)) * 64 + krd]);
                uf[fn] = *reinterpret_cast<const sh8*>(&Bu[(wn + fn * 16 + (lane & 15)) * 64 + krd]);
            }
            #pragma unroll
            for (int fm = 0; fm < 4; ++fm)
                #pragma unroll
                for (int fn = 0; fn < 2; ++fn) {
                    accg[fm][fn] = __builtin_amdgcn_mfma_f32_16x16x32_bf16(af[fm], gf[fn], accg[fm][fn], 0, 0, 0);
                    accu[fm][fn] = __builtin_amdgcn_mfma_f32_16x16x32_bf16(af[fm], uf[fn], accu[fm][fn], 0, 0, 0);
                }
        }
        __syncthreads();
    }

    #pragma unroll
    for (int fm = 0; fm < 4; ++fm)
        #pragma unroll
        for (int r = 0; r < 4; ++r) {
            int row = m0 + wm + fm * 16 + (lane >> 4) * 4 + r;
            #pragma unroll
            for (int fn = 0; fn < 2; ++fn) {
                int col = n0 + wn + fn * 16 + (lane & 15);
                float g = accg[fm][fn][r];
                float u = accu[fm][fn][r];
                H[(size_t)row * IDIM + col] = bf(g / (1.f + expf(-g)) * u);
            }
        }
}

// ---------------- GEMM2: H @ Wd^T, scale, atomicAdd ----------------
// tile 128x128, BK=64, 4 waves, wave-tile 64x64
template<bool W_BF16>
__global__ __launch_bounds__(256) void gemm2_kernel(
    const short* __restrict__ H, const short* __restrict__ Wd, const float* __restrict__ DP,
    const int* __restrict__ meta, const int* __restrict__ tlist_p, const float* __restrict__ wlist_p,
    float* __restrict__ out)
{
    int mt = blockIdx.x >> 3;
    int nt = blockIdx.x & 7;
    if (mt >= meta[33]) return;
    int e  = meta[64 + mt];
    int m0 = mt * 128, n0 = nt * 128;

    __shared__ short As[128 * 64];
    __shared__ short Bs[128 * 64];

    int tid = threadIdx.x, lane = tid & 63, wv = tid >> 6;
    int wm = (wv >> 1) * 64, wn = (wv & 1) * 64;

    f32x4 acc[4][4] = {};

    const float* drow = nullptr; int brow = 0, bcol = 0;
    if (!W_BF16) {
        brow = tid >> 1; bcol = (tid & 1) * 32;
        drow = DP + ((size_t)e * DIM + n0 + brow) * IDIM;
    }

    for (int k0 = 0; k0 < IDIM; k0 += 64) {
        #pragma unroll
        for (int j = 0; j < 4; ++j) {
            int ch = wv * 4 + j;
            int rr = ch * 8 + (lane >> 3);
            glds16(H + (size_t)(m0 + rr) * IDIM + k0 + (lane & 7) * 8, &As[ch * 512]);
        }
        if (W_BF16) {
            #pragma unroll
            for (int j = 0; j < 4; ++j) {
                int ch = wv * 4 + j;
                int rr = ch * 8 + (lane >> 3);
                glds16(Wd + ((size_t)e * DIM + n0 + rr) * IDIM + k0 + (lane & 7) * 8, &Bs[ch * 512]);
            }
        } else {
            #pragma unroll
            for (int j = 0; j < 4; ++j) {
                float4 a = *reinterpret_cast<const float4*>(drow + k0 + bcol + j * 8);
                float4 b = *reinterpret_cast<const float4*>(drow + k0 + bcol + j * 8 + 4);
                *reinterpret_cast<sh8*>(&Bs[brow * 64 + bcol + j * 8]) = pack8(a, b);
            }
        }
        __syncthreads();
        #pragma unroll
        for (int kk = 0; kk < 64; kk += 32) {
            int krd = kk + (lane >> 4) * 8;
            sh8 af[4], bq[4];
            #pragma unroll
            for (int fm = 0; fm < 4; ++fm)
                af[fm] = *reinterpret_cast<const sh8*>(&As[(wm + fm * 16 + (lane & 15)) * 64 + krd]);
            #pragma unroll
            for (int fn = 0; fn < 4; ++fn)
                bq[fn] = *reinterpret_cast<const sh8*>(&Bs[(wn + fn * 16 + (lane & 15)) * 64 + krd]);
            #pragma unroll
            for (int fm = 0; fm < 4; ++fm)
                #pragma unroll
                for (int fn = 0; fn < 4; ++fn)
                    acc[fm][fn] = __builtin_amdgcn_mfma_f32_16x16x32_bf16(af[fm], bq[fn], acc[fm][fn], 0, 0, 0);
        }
        __syncthreads();
    }

    #pragma unroll
    for (int fm = 0; fm < 4; ++fm)
        #pragma unroll
        for (int r = 0; r < 4; ++r) {
            int row = m0 + wm + fm * 16 + (lane >> 4) * 4 + r;
            int t     = tlist_p[row];
            float wgt = wlist_p[row];
            #pragma unroll
            for (int fn = 0; fn < 4; ++fn) {
                int col = n0 + wn + fn * 16 + (lane & 15);
                atomicAdd(&out[(size_t)t * DIM + col], acc[fm][fn][r] * wgt);
            }
        }
}

// ---------------- launch ----------------
extern "C" void kernel_launch(void* const* d_in, const int* in_sizes, int n_in,
                              void* d_out, int out_size, void* d_ws, size_t ws_size,
                              hipStream_t stream)
{
    const float* X    = (const float*)d_in[0];
    const float* GW   = (const float*)d_in[1];
    const float* GUP  = (const float*)d_in[2];
    const float* DP   = (const float*)d_in[3];
    const float* BIAS = (const float*)d_in[4];
    float* out = (float*)d_out;

    char* ws = (char*)d_ws;
    int*   meta     = (int*)ws;                       // 4 KB (offs_p/ntiles/tile2e/cnt)
    int*   cnt      = meta + 256;
    int*   topk_idx = (int*)(ws + (4u << 10));
    float* topk_w   = (float*)(ws + (68u << 10));
    int*   tlist_c  = (int*)(ws + (132u << 10));      // 512 KB
    float* wlist_c  = (float*)(ws + (644u << 10));    // 512 KB
    int*   tlist_p  = (int*)(ws + (1156u << 10));     // 80 KB
    float* wlist_p  = (float*)(ws + (1236u << 10));   // 80 KB

    constexpr size_t OFF_H   = 2ull << 20;
    constexpr size_t SZ_ROWS = (size_t)RPAD * IDIM * 2;       // 41943040
    constexpr size_t OFF_XG  = OFF_H + SZ_ROWS;               // 44040192
    constexpr size_t OFF_WGU = OFF_XG + SZ_ROWS;              // 85983232
    constexpr size_t OFF_WD  = OFF_WGU + GUP_ELEMS * 2;       // 220200960
    constexpr size_t END_ALL = OFF_WD + (ALL_ELEMS - GUP_ELEMS) * 2; // 287309824

    short* H   = (short*)(ws + OFF_H);
    short* Xg  = (short*)(ws + OFF_XG);
    short* Wgu = (short*)(ws + OFF_WGU);
    short* Wd  = (short*)(ws + OFF_WD);

    bool t1 = ws_size >= END_ALL;      // bf16 weights fit
    bool t2 = ws_size >= OFF_WGU;      // Xg fits

    (void)hipMemsetAsync(meta, 0, 4096, stream);
    (void)hipMemsetAsync(d_out, 0, (size_t)T_TOK * DIM * sizeof(float), stream);

    router_kernel<<<T_TOK / 4, 256, 0, stream>>>(X, GW, BIAS, topk_idx, topk_w);
    scatter_kernel<<<(T_TOK * TOPK + 255) / 256, 256, 0, stream>>>(topk_idx, topk_w, cnt, tlist_c, wlist_c);
    plan_kernel<<<1, 64, 0, stream>>>(meta);

    if (t1)
        convert_kernel<<<(int)(ALL_ELEMS / 8 / 256), 256, 0, stream>>>(GUP, DP, Wgu, Wd);

    if (t2) gather_kernel<true ><<<RPAD / 4, 256, 0, stream>>>(X, meta, tlist_c, wlist_c, Xg, tlist_p, wlist_p);
    else    gather_kernel<false><<<RPAD / 4, 256, 0, stream>>>(X, meta, tlist_c, wlist_c, Xg, tlist_p, wlist_p);

    int g1 = MAXT * 16;
    if (t1)      gemm1_kernel<true , true ><<<g1, 256, 0, stream>>>(Xg, X, Wgu, GUP, meta, tlist_p, H);
    else if (t2) gemm1_kernel<true , false><<<g1, 256, 0, stream>>>(Xg, X, Wgu, GUP, meta, tlist_p, H);
    else         gemm1_kernel<false, false><<<g1, 256, 0, stream>>>(Xg, X, Wgu, GUP, meta, tlist_p, H);

    int g2 = MAXT * 8;
    if (t1) gemm2_kernel<true ><<<g2, 256, 0, stream>>>(H, Wd, DP, meta, tlist_p, wlist_p, out);
    else    gemm2_kernel<false><<<g2, 256, 0, stream>>>(H, Wd, DP, meta, tlist_p, wlist_p, out);
}

// Round 3
// 482.340 us; speedup vs baseline: 1.5248x; 1.2252x over previous
//
#include <hip/hip_runtime.h>
#include <hip/hip_bf16.h>
#include <cstdint>
#include <cstddef>

#define T_TOK 4096
#define DIM   1024
#define IDIM  1024
#define NEXP  32
#define TOPK  4
#define MAXT  160            // max 128-row m-tiles: 16384/128 + 32
#define RPAD  (MAXT*128)     // 20480 padded rows max

typedef short sh8  __attribute__((ext_vector_type(8)));
typedef float f32x4 __attribute__((ext_vector_type(4)));

__device__ __forceinline__ short bf(float f) {
    union { float f; uint32_t u; } v; v.f = f;
    uint32_t r = (v.u + 0x7FFFu + ((v.u >> 16) & 1u)) >> 16;   // RNE
    return (short)r;
}
__device__ __forceinline__ float bf2f(short s) {
    union { uint32_t u; float f; } v; v.u = ((uint32_t)(uint16_t)s) << 16;
    return v.f;
}
__device__ __forceinline__ sh8 pack8(float4 a, float4 b) {
    sh8 r;
    r[0]=bf(a.x); r[1]=bf(a.y); r[2]=bf(a.z); r[3]=bf(a.w);
    r[4]=bf(b.x); r[5]=bf(b.y); r[6]=bf(b.z); r[7]=bf(b.w);
    return r;
}
__device__ __forceinline__ void glds16(const void* g, const void* l) {
    __builtin_amdgcn_global_load_lds((const __attribute__((address_space(1))) void*)g,
                                     (__attribute__((address_space(3))) void*)l, 16, 0, 0);
}

// ---------------- Router: one wave per token, fp32 ----------------
__global__ __launch_bounds__(256) void router_kernel(
    const float* __restrict__ X, const float* __restrict__ GW,
    const float* __restrict__ bias, int* __restrict__ topk_idx,
    float* __restrict__ topk_w)
{
    int wid  = threadIdx.x >> 6;
    int lane = threadIdx.x & 63;
    int t = blockIdx.x * 4 + wid;

    float4 h[4];
    const float4* xr = reinterpret_cast<const float4*>(X + (size_t)t * DIM);
    #pragma unroll
    for (int c = 0; c < 4; ++c) h[c] = xr[lane + 64 * c];

    float myscore = 0.f;
    for (int e = 0; e < NEXP; ++e) {
        const float4* gr = reinterpret_cast<const float4*>(GW + (size_t)e * DIM);
        float p = 0.f;
        #pragma unroll
        for (int c = 0; c < 4; ++c) {
            float4 g = gr[lane + 64 * c];
            p += h[c].x * g.x + h[c].y * g.y + h[c].z * g.z + h[c].w * g.w;
        }
        #pragma unroll
        for (int o = 32; o; o >>= 1) p += __shfl_xor(p, o);
        if (lane == e) myscore = p;
    }
    float rw = 1.f / (1.f + expf(-myscore));
    float sel = (lane < NEXP) ? rw + bias[lane] : -1e30f;

    float wsum = 0.f;
    int   oi = 0; float ow = 0.f;
    #pragma unroll
    for (int k = 0; k < TOPK; ++k) {
        float v = sel;
        int   idx = (lane < NEXP) ? lane : 9999;
        #pragma unroll
        for (int o = 32; o; o >>= 1) {
            float v2 = __shfl_xor(v, o);
            int   i2 = __shfl_xor(idx, o);
            if (v2 > v || (v2 == v && i2 < idx)) { v = v2; idx = i2; }
        }
        float wk = __shfl(rw, idx);
        wsum += wk;
        if (lane == k)   { oi = idx; ow = wk; }
        if (lane == idx) sel = -1e30f;
    }
    if (lane < TOPK) {
        topk_idx[t * TOPK + lane] = oi;
        topk_w  [t * TOPK + lane] = ow / (wsum + 1e-6f);
    }
}

// ---------------- Scatter: per-expert compact lists + back-map ----------------
__global__ void scatter_kernel(const int* __restrict__ topk_idx,
                               int* __restrict__ cnt,
                               int* __restrict__ tlist_c,
                               int* __restrict__ posmap)
{
    int gid = blockIdx.x * blockDim.x + threadIdx.x;
    if (gid >= T_TOK * TOPK) return;
    int e = topk_idx[gid];
    int pos = atomicAdd(&cnt[e], 1);
    tlist_c[e * T_TOK + pos] = gid >> 2;
    posmap[gid] = pos;        // values identical regardless of atomic order -> deterministic output
}

// meta[0..31]=padded offs, meta[33]=ntiles, meta[34]=rows_pad, meta[64+t]=tile2e, meta[256+e]=cnt
__global__ void plan_kernel(int* __restrict__ meta)
{
    if (threadIdx.x == 0) {
        int acc = 0, t = 0;
        for (int e = 0; e < NEXP; ++e) {
            meta[e] = acc;
            int c = meta[256 + e];
            int ntl = (c + 127) >> 7;
            for (int i = 0; i < ntl; ++i) meta[64 + t++] = e;
            acc += ntl * 128;
        }
        meta[32] = acc;
        meta[33] = t;
        meta[34] = acc;
    }
}

// ---------------- Gather: padded tlist (+ optional Xg bf16) ----------------
template<bool DO_XG>
__global__ __launch_bounds__(256) void gather_kernel(
    const float* __restrict__ X, const int* __restrict__ meta,
    const int* __restrict__ tlist_c,
    short* __restrict__ Xg, int* __restrict__ tlist_p)
{
    int wid = threadIdx.x >> 6, lane = threadIdx.x & 63;
    int r = blockIdx.x * 4 + wid;
    if (r >= meta[34]) return;
    int e  = meta[64 + (r >> 7)];
    int li = r - meta[e];
    bool real = li < meta[256 + e];
    int t = 0;
    if (real) t = tlist_c[e * T_TOK + li];
    if (lane == 0) tlist_p[r] = t;
    if (DO_XG) {
        const float4* src = reinterpret_cast<const float4*>(X + (size_t)t * DIM);
        sh8* dst = reinterpret_cast<sh8*>(Xg + (size_t)r * DIM);
        float4 z = make_float4(0.f, 0.f, 0.f, 0.f);
        #pragma unroll
        for (int it = 0; it < 2; ++it) {
            int si = it * 64 + lane;
            float4 a = real ? src[2 * si]     : z;
            float4 b = real ? src[2 * si + 1] : z;
            dst[si] = pack8(a, b);
        }
    }
}

// ---------------- Weight convert fp32 -> bf16 (tier1) ----------------
#define GUP_ELEMS 67108864ull   // 32*2048*1024
#define ALL_ELEMS 100663296ull  // + 32*1024*1024
__global__ __launch_bounds__(256) void convert_kernel(
    const float* __restrict__ gup, const float* __restrict__ dp,
    short* __restrict__ wgu, short* __restrict__ wd)
{
    size_t i = ((size_t)blockIdx.x * 256 + threadIdx.x) * 8;
    const float* src; short* dst;
    if (i < GUP_ELEMS) { src = gup + i; dst = wgu + i; }
    else               { src = dp + (i - GUP_ELEMS); dst = wd + (i - GUP_ELEMS); }
    float4 a = *reinterpret_cast<const float4*>(src);
    float4 b = *reinterpret_cast<const float4*>(src + 4);
    *reinterpret_cast<sh8*>(dst) = pack8(a, b);
}

// ---------------- GEMM1: Xg @ Wgu^T (g,u fused), silu, H bf16 ----------------
// 128(M) x 64(N, x2 for g/u) tile, BK=64, dbuf LDS, single barrier/K-step,
// T2 XOR-swizzle (write via pre-swizzled global col, read via XOR'd index).
template<bool A_GLDS, bool W_BF16>
__global__ __launch_bounds__(256) void gemm1_kernel(
    const short* __restrict__ Xg, const float* __restrict__ X,
    const short* __restrict__ Wgu, const float* __restrict__ GUP,
    const int* __restrict__ meta, const int* __restrict__ tlist_p,
    short* __restrict__ H)
{
    int mt = blockIdx.x >> 4;
    int nt = blockIdx.x & 15;
    if (mt >= meta[33]) return;
    int e  = meta[64 + mt];
    int m0 = mt * 128, n0 = nt * 64;

    __shared__ short As[2][128 * 64];
    __shared__ short Bg[2][64 * 64];
    __shared__ short Bu[2][64 * 64];

    int tid = threadIdx.x, lane = tid & 63, wv = tid >> 6;
    int wm = (wv >> 1) * 64, wn = (wv & 1) * 32;

    f32x4 accg[4][2] = {};
    f32x4 accu[4][2] = {};

    int swcol = ((lane & 7) ^ (lane >> 3)) * 8;  // pre-swizzled global col (elems)
    const float* xrow = nullptr; int arow = 0, acol = 0;
    if (!A_GLDS) {
        arow = tid >> 1; acol = (tid & 1) * 32;
        xrow = X + (size_t)tlist_p[m0 + arow] * DIM;
    }
    const float *grow = nullptr, *urow = nullptr;
    int brow = tid >> 2, bcol = (tid & 3) * 16;
    if (!W_BF16) {
        grow = GUP + ((size_t)e * 2 * IDIM + n0 + brow) * DIM;
        urow = GUP + ((size_t)e * 2 * IDIM + IDIM + n0 + brow) * DIM;
    }
    const short* gb = Wgu + ((size_t)e * 2 * IDIM + n0) * DIM;
    const short* ub = Wgu + ((size_t)e * 2 * IDIM + IDIM + n0) * DIM;

    auto stage = [&](int b, int k0) {
        if (A_GLDS) {
            #pragma unroll
            for (int j = 0; j < 4; ++j) {
                int ch = wv * 4 + j;
                glds16(Xg + (size_t)(m0 + ch * 8 + (lane >> 3)) * DIM + k0 + swcol, &As[b][ch * 512]);
            }
        } else {
            #pragma unroll
            for (int j = 0; j < 4; ++j) {
                int c = acol + j * 8;
                float4 a  = *reinterpret_cast<const float4*>(xrow + k0 + c);
                float4 bv = *reinterpret_cast<const float4*>(xrow + k0 + c + 4);
                *reinterpret_cast<sh8*>(&As[b][arow * 64 + (c ^ ((arow & 7) << 3))]) = pack8(a, bv);
            }
        }
        if (W_BF16) {
            #pragma unroll
            for (int j = 0; j < 2; ++j) {
                int ch = wv * 2 + j;
                glds16(gb + (size_t)(ch * 8 + (lane >> 3)) * DIM + k0 + swcol, &Bg[b][ch * 512]);
                glds16(ub + (size_t)(ch * 8 + (lane >> 3)) * DIM + k0 + swcol, &Bu[b][ch * 512]);
            }
        } else {
            #pragma unroll
            for (int j = 0; j < 2; ++j) {
                int c = bcol + j * 8;
                float4 a  = *reinterpret_cast<const float4*>(grow + k0 + c);
                float4 bv = *reinterpret_cast<const float4*>(grow + k0 + c + 4);
                *reinterpret_cast<sh8*>(&Bg[b][brow * 64 + (c ^ ((brow & 7) << 3))]) = pack8(a, bv);
                a  = *reinterpret_cast<const float4*>(urow + k0 + c);
                bv = *reinterpret_cast<const float4*>(urow + k0 + c + 4);
                *reinterpret_cast<sh8*>(&Bu[b][brow * 64 + (c ^ ((brow & 7) << 3))]) = pack8(a, bv);
            }
        }
    };

    stage(0, 0);
    int cur = 0;
    int swr = (lane & 7) << 3;   // row&7 == lane&7 for all fragment rows
    for (int it = 0; it < DIM / 64; ++it) {
        asm volatile("s_waitcnt vmcnt(0)" ::: "memory");
        __syncthreads();
        if (it + 1 < DIM / 64) stage(cur ^ 1, (it + 1) * 64);
        #pragma unroll
        for (int kk = 0; kk < 64; kk += 32) {
            int ki = (kk + (lane >> 4) * 8) ^ swr;
            sh8 af[4], gf[2], uf[2];
            #pragma unroll
            for (int fm = 0; fm < 4; ++fm)
                af[fm] = *reinterpret_cast<const sh8*>(&As[cur][(wm + fm * 16 + (lane & 15)) * 64 + ki]);
            #pragma unroll
            for (int fn = 0; fn < 2; ++fn) {
                gf[fn] = *reinterpret_cast<const sh8*>(&Bg[cur][(wn + fn * 16 + (lane & 15)) * 64 + ki]);
                uf[fn] = *reinterpret_cast<const sh8*>(&Bu[cur][(wn + fn * 16 + (lane & 15)) * 64 + ki]);
            }
            #pragma unroll
            for (int fm = 0; fm < 4; ++fm)
                #pragma unroll
                for (int fn = 0; fn < 2; ++fn) {
                    accg[fm][fn] = __builtin_amdgcn_mfma_f32_16x16x32_bf16(af[fm], gf[fn], accg[fm][fn], 0, 0, 0);
                    accu[fm][fn] = __builtin_amdgcn_mfma_f32_16x16x32_bf16(af[fm], uf[fn], accu[fm][fn], 0, 0, 0);
                }
        }
        cur ^= 1;
    }

    #pragma unroll
    for (int fm = 0; fm < 4; ++fm)
        #pragma unroll
        for (int r = 0; r < 4; ++r) {
            int row = m0 + wm + fm * 16 + (lane >> 4) * 4 + r;
            #pragma unroll
            for (int fn = 0; fn < 2; ++fn) {
                int col = n0 + wn + fn * 16 + (lane & 15);
                float g = accg[fm][fn][r];
                float u = accu[fm][fn][r];
                H[(size_t)row * IDIM + col] = bf(g / (1.f + expf(-g)) * u);
            }
        }
}

// ---------------- GEMM2: H @ Wd^T -> Y (no atomics) ----------------
template<bool W_BF16, bool Y_F32>
__global__ __launch_bounds__(256) void gemm2_kernel(
    const short* __restrict__ H, const short* __restrict__ Wd, const float* __restrict__ DP,
    const int* __restrict__ meta, float* __restrict__ Yf, short* __restrict__ Yb)
{
    int mt = blockIdx.x >> 3;
    int nt = blockIdx.x & 7;
    if (mt >= meta[33]) return;
    int e  = meta[64 + mt];
    int m0 = mt * 128, n0 = nt * 128;

    __shared__ short As[2][128 * 64];
    __shared__ short Bs[2][128 * 64];

    int tid = threadIdx.x, lane = tid & 63, wv = tid >> 6;
    int wm = (wv >> 1) * 64, wn = (wv & 1) * 64;

    f32x4 acc[4][4] = {};

    int swcol = ((lane & 7) ^ (lane >> 3)) * 8;
    const float* drow = nullptr; int brow = 0, bcol = 0;
    if (!W_BF16) {
        brow = tid >> 1; bcol = (tid & 1) * 32;
        drow = DP + ((size_t)e * DIM + n0 + brow) * IDIM;
    }
    const short* db = Wd + ((size_t)e * DIM + n0) * IDIM;

    auto stage = [&](int b, int k0) {
        #pragma unroll
        for (int j = 0; j < 4; ++j) {
            int ch = wv * 4 + j;
            glds16(H + (size_t)(m0 + ch * 8 + (lane >> 3)) * IDIM + k0 + swcol, &As[b][ch * 512]);
        }
        if (W_BF16) {
            #pragma unroll
            for (int j = 0; j < 4; ++j) {
                int ch = wv * 4 + j;
                glds16(db + (size_t)(ch * 8 + (lane >> 3)) * IDIM + k0 + swcol, &Bs[b][ch * 512]);
            }
        } else {
            #pragma unroll
            for (int j = 0; j < 4; ++j) {
                int c = bcol + j * 8;
                float4 a  = *reinterpret_cast<const float4*>(drow + k0 + c);
                float4 bv = *reinterpret_cast<const float4*>(drow + k0 + c + 4);
                *reinterpret_cast<sh8*>(&Bs[b][brow * 64 + (c ^ ((brow & 7) << 3))]) = pack8(a, bv);
            }
        }
    };

    stage(0, 0);
    int cur = 0;
    int swr = (lane & 7) << 3;
    for (int it = 0; it < IDIM / 64; ++it) {
        asm volatile("s_waitcnt vmcnt(0)" ::: "memory");
        __syncthreads();
        if (it + 1 < IDIM / 64) stage(cur ^ 1, (it + 1) * 64);
        #pragma unroll
        for (int kk = 0; kk < 64; kk += 32) {
            int ki = (kk + (lane >> 4) * 8) ^ swr;
            sh8 af[4], bq[4];
            #pragma unroll
            for (int fm = 0; fm < 4; ++fm)
                af[fm] = *reinterpret_cast<const sh8*>(&As[cur][(wm + fm * 16 + (lane & 15)) * 64 + ki]);
            #pragma unroll
            for (int fn = 0; fn < 4; ++fn)
                bq[fn] = *reinterpret_cast<const sh8*>(&Bs[cur][(wn + fn * 16 + (lane & 15)) * 64 + ki]);
            #pragma unroll
            for (int fm = 0; fm < 4; ++fm)
                #pragma unroll
                for (int fn = 0; fn < 4; ++fn)
                    acc[fm][fn] = __builtin_amdgcn_mfma_f32_16x16x32_bf16(af[fm], bq[fn], acc[fm][fn], 0, 0, 0);
        }
        cur ^= 1;
    }

    #pragma unroll
    for (int fm = 0; fm < 4; ++fm)
        #pragma unroll
        for (int r = 0; r < 4; ++r) {
            int row = m0 + wm + fm * 16 + (lane >> 4) * 4 + r;
            #pragma unroll
            for (int fn = 0; fn < 4; ++fn) {
                int col = n0 + wn + fn * 16 + (lane & 15);
                if (Y_F32) Yf[(size_t)row * DIM + col] = acc[fm][fn][r];
                else       Yb[(size_t)row * DIM + col] = bf(acc[fm][fn][r]);
            }
        }
}

// ---------------- Combine: out[t] = sum_k w_k * Y[row(t,k)] ----------------
template<bool Y_F32>
__global__ __launch_bounds__(256) void combine_kernel(
    const float* __restrict__ Yf, const short* __restrict__ Yb,
    const int* __restrict__ meta, const int* __restrict__ topk_idx,
    const float* __restrict__ topk_w, const int* __restrict__ posmap,
    float* __restrict__ out)
{
    int t = blockIdx.x;
    int d = threadIdx.x * 4;
    float4 acc = make_float4(0.f, 0.f, 0.f, 0.f);
    #pragma unroll
    for (int k = 0; k < TOPK; ++k) {
        int gid = t * TOPK + k;
        int e   = topk_idx[gid];
        int row = meta[e] + posmap[gid];
        float w = topk_w[gid];
        if (Y_F32) {
            float4 y = *reinterpret_cast<const float4*>(Yf + (size_t)row * DIM + d);
            acc.x += w * y.x; acc.y += w * y.y; acc.z += w * y.z; acc.w += w * y.w;
        } else {
            short4 y = *reinterpret_cast<const short4*>(Yb + (size_t)row * DIM + d);
            acc.x += w * bf2f(y.x); acc.y += w * bf2f(y.y);
            acc.z += w * bf2f(y.z); acc.w += w * bf2f(y.w);
        }
    }
    *reinterpret_cast<float4*>(out + (size_t)t * DIM + d) = acc;
}

// ---------------- launch ----------------
extern "C" void kernel_launch(void* const* d_in, const int* in_sizes, int n_in,
                              void* d_out, int out_size, void* d_ws, size_t ws_size,
                              hipStream_t stream)
{
    const float* X    = (const float*)d_in[0];
    const float* GW   = (const float*)d_in[1];
    const float* GUP  = (const float*)d_in[2];
    const float* DP   = (const float*)d_in[3];
    const float* BIAS = (const float*)d_in[4];
    float* out = (float*)d_out;

    char* ws = (char*)d_ws;
    int*   meta     = (int*)ws;                       // 4 KB
    int*   cnt      = meta + 256;
    int*   topk_idx = (int*)(ws + (4u   << 10));      // 64 KB
    float* topk_w   = (float*)(ws + (68u  << 10));    // 64 KB
    int*   posmap   = (int*)(ws + (132u << 10));      // 64 KB
    int*   tlist_c  = (int*)(ws + (196u << 10));      // 512 KB
    int*   tlist_p  = (int*)(ws + (708u << 10));      // 80 KB

    constexpr size_t OFF_H   = 2ull << 20;
    constexpr size_t SZ_ROWS = (size_t)RPAD * IDIM * 2;             // 40 MB
    constexpr size_t OFF_XG  = OFF_H + SZ_ROWS;
    constexpr size_t OFF_WGU = OFF_XG + SZ_ROWS;
    constexpr size_t OFF_WD  = OFF_WGU + GUP_ELEMS * 2;
    constexpr size_t END_ALL = OFF_WD + (ALL_ELEMS - GUP_ELEMS) * 2; // 287309824
    constexpr size_t SZ_YF   = (size_t)RPAD * DIM * 4;              // 80 MB

    short* H   = (short*)(ws + OFF_H);
    short* Xg  = (short*)(ws + OFF_XG);
    short* Wgu = (short*)(ws + OFF_WGU);
    short* Wd  = (short*)(ws + OFF_WD);
    float* Yf  = (float*)(ws + END_ALL);
    short* Yb  = Xg;                                  // Xg dead after gemm1

    bool t1   = ws_size >= END_ALL;
    bool t2   = ws_size >= OFF_WGU;
    bool yf32 = ws_size >= END_ALL + SZ_YF;

    (void)hipMemsetAsync(meta, 0, 4096, stream);

    router_kernel<<<T_TOK / 4, 256, 0, stream>>>(X, GW, BIAS, topk_idx, topk_w);
    scatter_kernel<<<(T_TOK * TOPK + 255) / 256, 256, 0, stream>>>(topk_idx, cnt, tlist_c, posmap);
    plan_kernel<<<1, 64, 0, stream>>>(meta);

    if (t1)
        convert_kernel<<<(int)(ALL_ELEMS / 8 / 256), 256, 0, stream>>>(GUP, DP, Wgu, Wd);

    if (t2) gather_kernel<true ><<<RPAD / 4, 256, 0, stream>>>(X, meta, tlist_c, Xg, tlist_p);
    else    gather_kernel<false><<<RPAD / 4, 256, 0, stream>>>(X, meta, tlist_c, Xg, tlist_p);

    int g1 = MAXT * 16;
    if (t1)      gemm1_kernel<true , true ><<<g1, 256, 0, stream>>>(Xg, X, Wgu, GUP, meta, tlist_p, H);
    else if (t2) gemm1_kernel<true , false><<<g1, 256, 0, stream>>>(Xg, X, Wgu, GUP, meta, tlist_p, H);
    else         gemm1_kernel<false, false><<<g1, 256, 0, stream>>>(Xg, X, Wgu, GUP, meta, tlist_p, H);

    int g2 = MAXT * 8;
    if (t1) {
        if (yf32) gemm2_kernel<true , true ><<<g2, 256, 0, stream>>>(H, Wd, DP, meta, Yf, Yb);
        else      gemm2_kernel<true , false><<<g2, 256, 0, stream>>>(H, Wd, DP, meta, Yf, Yb);
    } else {
        if (yf32) gemm2_kernel<false, true ><<<g2, 256, 0, stream>>>(H, Wd, DP, meta, Yf, Yb);
        else      gemm2_kernel<false, false><<<g2, 256, 0, stream>>>(H, Wd, DP, meta, Yf, Yb);
    }

    if (yf32) combine_kernel<true ><<<T_TOK, 256, 0, stream>>>(Yf, Yb, meta, topk_idx, topk_w, posmap, out);
    else      combine_kernel<false><<<T_TOK, 256, 0, stream>>>(Yf, Yb, meta, topk_idx, topk_w, posmap, out);
}

// Round 4
// 379.714 us; speedup vs baseline: 1.9369x; 1.2703x over previous
//
#include <hip/hip_runtime.h>
#include <hip/hip_bf16.h>
#include <cstdint>
#include <cstddef>

#define T_TOK 4096
#define DIM   1024
#define IDIM  1024
#define NEXP  32
#define TOPK  4
#define MAXT  160            // max 128-row m-tiles
#define RPAD  (MAXT*128)     // 20480 padded rows max

#define GUP_ELEMS 67108864ull   // 32*2048*1024
#define ALL_ELEMS 100663296ull  // + 32*1024*1024
#define CONV_BLOCKS 49152       // ALL_ELEMS / (256*8)
#define ROUTER_BLOCKS (T_TOK/4)

typedef short sh8  __attribute__((ext_vector_type(8)));
typedef float f32x4 __attribute__((ext_vector_type(4)));

__device__ __forceinline__ short bf(float f) {
    union { float f; uint32_t u; } v; v.f = f;
    uint32_t r = (v.u + 0x7FFFu + ((v.u >> 16) & 1u)) >> 16;   // RNE
    return (short)r;
}
__device__ __forceinline__ float bf2f(short s) {
    union { uint32_t u; float f; } v; v.u = ((uint32_t)(uint16_t)s) << 16;
    return v.f;
}
__device__ __forceinline__ sh8 pack8(float4 a, float4 b) {
    sh8 r;
    r[0]=bf(a.x); r[1]=bf(a.y); r[2]=bf(a.z); r[3]=bf(a.w);
    r[4]=bf(b.x); r[5]=bf(b.y); r[6]=bf(b.z); r[7]=bf(b.w);
    return r;
}
__device__ __forceinline__ void glds16(const void* g, const void* l) {
    __builtin_amdgcn_global_load_lds((const __attribute__((address_space(1))) void*)g,
                                     (__attribute__((address_space(3))) void*)l, 16, 0, 0);
}

// Per-block plan recompute: which expert owns m-tile `mt`; tile_start = first tile of e.
// Returns -1 if mt beyond total tiles. Padded row base of expert e == tile_start*128.
__device__ __forceinline__ int tile_expert(const int* __restrict__ cnt, int mt, int& tile_start) {
    int s = 0, e = -1, ts = 0;
    #pragma unroll
    for (int i = 0; i < NEXP; ++i) {
        int t = (cnt[i] + 127) >> 7;
        if (mt >= s && mt < s + t) { e = i; ts = s; }
        s += t;
    }
    tile_start = ts;
    return e;
}

// ---------------- Fat front kernel: weight convert + router(+scatter) ----------------
template<bool DO_CONV>
__global__ __launch_bounds__(256) void front_kernel(
    const float* __restrict__ X, const float* __restrict__ GW,
    const float* __restrict__ bias,
    const float* __restrict__ gup, const float* __restrict__ dp,
    short* __restrict__ wgu, short* __restrict__ wd,
    int* __restrict__ topk_idx, float* __restrict__ topk_w,
    int* __restrict__ cnt, int* __restrict__ tlist_c, int* __restrict__ posmap)
{
    if (DO_CONV && blockIdx.x < CONV_BLOCKS) {
        size_t i = ((size_t)blockIdx.x * 256 + threadIdx.x) * 8;
        const float* src; short* dst;
        if (i < GUP_ELEMS) { src = gup + i; dst = wgu + i; }
        else               { src = dp + (i - GUP_ELEMS); dst = wd + (i - GUP_ELEMS); }
        float4 a = *reinterpret_cast<const float4*>(src);
        float4 b = *reinterpret_cast<const float4*>(src + 4);
        *reinterpret_cast<sh8*>(dst) = pack8(a, b);
        return;
    }
    int rb = DO_CONV ? (int)blockIdx.x - CONV_BLOCKS : (int)blockIdx.x;

    int wid  = threadIdx.x >> 6;
    int lane = threadIdx.x & 63;
    int t = rb * 4 + wid;

    float4 h[4];
    const float4* xr = reinterpret_cast<const float4*>(X + (size_t)t * DIM);
    #pragma unroll
    for (int c = 0; c < 4; ++c) h[c] = xr[lane + 64 * c];

    float myscore = 0.f;
    for (int e = 0; e < NEXP; ++e) {
        const float4* gr = reinterpret_cast<const float4*>(GW + (size_t)e * DIM);
        float p = 0.f;
        #pragma unroll
        for (int c = 0; c < 4; ++c) {
            float4 g = gr[lane + 64 * c];
            p += h[c].x * g.x + h[c].y * g.y + h[c].z * g.z + h[c].w * g.w;
        }
        #pragma unroll
        for (int o = 32; o; o >>= 1) p += __shfl_xor(p, o);
        if (lane == e) myscore = p;
    }
    float rw = 1.f / (1.f + expf(-myscore));
    float sel = (lane < NEXP) ? rw + bias[lane] : -1e30f;

    float wsum = 0.f;
    int   oi = 0; float ow = 0.f;
    #pragma unroll
    for (int k = 0; k < TOPK; ++k) {
        float v = sel;
        int   idx = (lane < NEXP) ? lane : 9999;
        #pragma unroll
        for (int o = 32; o; o >>= 1) {
            float v2 = __shfl_xor(v, o);
            int   i2 = __shfl_xor(idx, o);
            if (v2 > v || (v2 == v && i2 < idx)) { v = v2; idx = i2; }
        }
        float wk = __shfl(rw, idx);
        wsum += wk;
        if (lane == k)   { oi = idx; ow = wk; }
        if (lane == idx) sel = -1e30f;
    }
    if (lane < TOPK) {
        int gid = t * TOPK + lane;
        topk_idx[gid] = oi;
        topk_w  [gid] = ow / (wsum + 1e-6f);
        int pos = atomicAdd(&cnt[oi], 1);   // order-nondeterministic, consumption is order-invariant
        tlist_c[oi * T_TOK + pos] = t;
        posmap[gid] = pos;
    }
}

// ---------------- Gather: padded tlist (+ optional Xg bf16) ----------------
template<bool DO_XG>
__global__ __launch_bounds__(256) void gather_kernel(
    const float* __restrict__ X, const int* __restrict__ cnt,
    const int* __restrict__ tlist_c,
    short* __restrict__ Xg, int* __restrict__ tlist_p)
{
    int wid = threadIdx.x >> 6, lane = threadIdx.x & 63;
    int r = blockIdx.x * 4 + wid;
    int ts;
    int e = tile_expert(cnt, r >> 7, ts);
    if (e < 0) return;
    int li = r - (ts << 7);
    bool real = li < cnt[e];
    int t = real ? tlist_c[e * T_TOK + li] : 0;
    if (lane == 0) tlist_p[r] = t;
    if (DO_XG) {
        const float4* src = reinterpret_cast<const float4*>(X + (size_t)t * DIM);
        sh8* dst = reinterpret_cast<sh8*>(Xg + (size_t)r * DIM);
        float4 z = make_float4(0.f, 0.f, 0.f, 0.f);
        #pragma unroll
        for (int it = 0; it < 2; ++it) {
            int si = it * 64 + lane;
            float4 a = real ? src[2 * si]     : z;
            float4 b = real ? src[2 * si + 1] : z;
            dst[si] = pack8(a, b);
        }
    }
}

// ---------------- GEMM1: Xg @ Wgu^T (g,u fused), silu, H bf16 ----------------
// m97-classic: 128(M) x 64(N, x2 g/u), BK=64, SINGLE-buffered 32KB LDS,
// two barriers/K-step, glds16 staging, T2 swizzle, 5 blocks/CU.
template<bool A_GLDS, bool W_BF16>
__global__ __launch_bounds__(256, 4) void gemm1_kernel(
    const short* __restrict__ Xg, const float* __restrict__ X,
    const short* __restrict__ Wgu, const float* __restrict__ GUP,
    const int* __restrict__ cnt, const int* __restrict__ tlist_p,
    short* __restrict__ H)
{
    // XCD swizzle: 16 n-tiles of one m-panel stay on one XCD (grid 2560 % 8 == 0)
    int bid = (blockIdx.x & 7) * (MAXT * 16 / 8) + (blockIdx.x >> 3);
    int mt = bid >> 4;
    int nt = bid & 15;
    int ts;
    int e = tile_expert(cnt, mt, ts);
    if (e < 0) return;
    int m0 = mt * 128, n0 = nt * 64;

    __shared__ short As[128 * 64];
    __shared__ short Bg[64 * 64];
    __shared__ short Bu[64 * 64];

    int tid = threadIdx.x, lane = tid & 63, wv = tid >> 6;
    int wm = (wv >> 1) * 64, wn = (wv & 1) * 32;

    f32x4 accg[4][2] = {};
    f32x4 accu[4][2] = {};

    int swcol = ((lane & 7) ^ (lane >> 3)) * 8;  // pre-swizzled global col (elems)
    const float* xrow = nullptr; int arow = 0, acol = 0;
    if (!A_GLDS) {
        arow = tid >> 1; acol = (tid & 1) * 32;
        xrow = X + (size_t)tlist_p[m0 + arow] * DIM;
    }
    const float *grow = nullptr, *urow = nullptr;
    int brow = tid >> 2, bcol = (tid & 3) * 16;
    if (!W_BF16) {
        grow = GUP + ((size_t)e * 2 * IDIM + n0 + brow) * DIM;
        urow = GUP + ((size_t)e * 2 * IDIM + IDIM + n0 + brow) * DIM;
    }
    const short* gb = Wgu + ((size_t)e * 2 * IDIM + n0) * DIM;
    const short* ub = Wgu + ((size_t)e * 2 * IDIM + IDIM + n0) * DIM;

    auto stage = [&](int k0) {
        if (A_GLDS) {
            #pragma unroll
            for (int j = 0; j < 4; ++j) {
                int ch = wv * 4 + j;
                glds16(Xg + (size_t)(m0 + ch * 8 + (lane >> 3)) * DIM + k0 + swcol, &As[ch * 512]);
            }
        } else {
            #pragma unroll
            for (int j = 0; j < 4; ++j) {
                int c = acol + j * 8;
                float4 a  = *reinterpret_cast<const float4*>(xrow + k0 + c);
                float4 bv = *reinterpret_cast<const float4*>(xrow + k0 + c + 4);
                *reinterpret_cast<sh8*>(&As[arow * 64 + (c ^ ((arow & 7) << 3))]) = pack8(a, bv);
            }
        }
        if (W_BF16) {
            #pragma unroll
            for (int j = 0; j < 2; ++j) {
                int ch = wv * 2 + j;
                glds16(gb + (size_t)(ch * 8 + (lane >> 3)) * DIM + k0 + swcol, &Bg[ch * 512]);
                glds16(ub + (size_t)(ch * 8 + (lane >> 3)) * DIM + k0 + swcol, &Bu[ch * 512]);
            }
        } else {
            #pragma unroll
            for (int j = 0; j < 2; ++j) {
                int c = bcol + j * 8;
                float4 a  = *reinterpret_cast<const float4*>(grow + k0 + c);
                float4 bv = *reinterpret_cast<const float4*>(grow + k0 + c + 4);
                *reinterpret_cast<sh8*>(&Bg[brow * 64 + (c ^ ((brow & 7) << 3))]) = pack8(a, bv);
                a  = *reinterpret_cast<const float4*>(urow + k0 + c);
                bv = *reinterpret_cast<const float4*>(urow + k0 + c + 4);
                *reinterpret_cast<sh8*>(&Bu[brow * 64 + (c ^ ((brow & 7) << 3))]) = pack8(a, bv);
            }
        }
    };

    int swr = (lane & 7) << 3;
    for (int it = 0; it < DIM / 64; ++it) {
        stage(it * 64);
        __syncthreads();                       // compiler drains vmcnt(0) here
        #pragma unroll
        for (int kk = 0; kk < 64; kk += 32) {
            int ki = (kk + (lane >> 4) * 8) ^ swr;
            sh8 af[4], gf[2], uf[2];
            #pragma unroll
            for (int fm = 0; fm < 4; ++fm)
                af[fm] = *reinterpret_cast<const sh8*>(&As[(wm + fm * 16 + (lane & 15)) * 64 + ki]);
            #pragma unroll
            for (int fn = 0; fn < 2; ++fn) {
                gf[fn] = *reinterpret_cast<const sh8*>(&Bg[(wn + fn * 16 + (lane & 15)) * 64 + ki]);
                uf[fn] = *reinterpret_cast<const sh8*>(&Bu[(wn + fn * 16 + (lane & 15)) * 64 + ki]);
            }
            #pragma unroll
            for (int fm = 0; fm < 4; ++fm)
                #pragma unroll
                for (int fn = 0; fn < 2; ++fn) {
                    accg[fm][fn] = __builtin_amdgcn_mfma_f32_16x16x32_bf16(af[fm], gf[fn], accg[fm][fn], 0, 0, 0);
                    accu[fm][fn] = __builtin_amdgcn_mfma_f32_16x16x32_bf16(af[fm], uf[fn], accu[fm][fn], 0, 0, 0);
                }
        }
        __syncthreads();                       // reads done before next stage overwrites
    }

    #pragma unroll
    for (int fm = 0; fm < 4; ++fm)
        #pragma unroll
        for (int r = 0; r < 4; ++r) {
            int row = m0 + wm + fm * 16 + (lane >> 4) * 4 + r;
            #pragma unroll
            for (int fn = 0; fn < 2; ++fn) {
                int col = n0 + wn + fn * 16 + (lane & 15);
                float g = accg[fm][fn][r];
                float u = accu[fm][fn][r];
                H[(size_t)row * IDIM + col] = bf(g / (1.f + expf(-g)) * u);
            }
        }
}

// ---------------- GEMM2: H @ Wd^T -> Y (no atomics), m97-classic ----------------
template<bool W_BF16, bool Y_F32>
__global__ __launch_bounds__(256, 4) void gemm2_kernel(
    const short* __restrict__ H, const short* __restrict__ Wd, const float* __restrict__ DP,
    const int* __restrict__ cnt, float* __restrict__ Yf, short* __restrict__ Yb)
{
    int bid = (blockIdx.x & 7) * (MAXT * 8 / 8) + (blockIdx.x >> 3);
    int mt = bid >> 3;
    int nt = bid & 7;
    int ts;
    int e = tile_expert(cnt, mt, ts);
    if (e < 0) return;
    int m0 = mt * 128, n0 = nt * 128;

    __shared__ short As[128 * 64];
    __shared__ short Bs[128 * 64];

    int tid = threadIdx.x, lane = tid & 63, wv = tid >> 6;
    int wm = (wv >> 1) * 64, wn = (wv & 1) * 64;

    f32x4 acc[4][4] = {};

    int swcol = ((lane & 7) ^ (lane >> 3)) * 8;
    const float* drow = nullptr; int brow = 0, bcol = 0;
    if (!W_BF16) {
        brow = tid >> 1; bcol = (tid & 1) * 32;
        drow = DP + ((size_t)e * DIM + n0 + brow) * IDIM;
    }
    const short* db = Wd + ((size_t)e * DIM + n0) * IDIM;

    auto stage = [&](int k0) {
        #pragma unroll
        for (int j = 0; j < 4; ++j) {
            int ch = wv * 4 + j;
            glds16(H + (size_t)(m0 + ch * 8 + (lane >> 3)) * IDIM + k0 + swcol, &As[ch * 512]);
        }
        if (W_BF16) {
            #pragma unroll
            for (int j = 0; j < 4; ++j) {
                int ch = wv * 4 + j;
                glds16(db + (size_t)(ch * 8 + (lane >> 3)) * IDIM + k0 + swcol, &Bs[ch * 512]);
            }
        } else {
            #pragma unroll
            for (int j = 0; j < 4; ++j) {
                int c = bcol + j * 8;
                float4 a  = *reinterpret_cast<const float4*>(drow + k0 + c);
                float4 bv = *reinterpret_cast<const float4*>(drow + k0 + c + 4);
                *reinterpret_cast<sh8*>(&Bs[brow * 64 + (c ^ ((brow & 7) << 3))]) = pack8(a, bv);
            }
        }
    };

    int swr = (lane & 7) << 3;
    for (int it = 0; it < IDIM / 64; ++it) {
        stage(it * 64);
        __syncthreads();
        #pragma unroll
        for (int kk = 0; kk < 64; kk += 32) {
            int ki = (kk + (lane >> 4) * 8) ^ swr;
            sh8 af[4], bq[4];
            #pragma unroll
            for (int fm = 0; fm < 4; ++fm)
                af[fm] = *reinterpret_cast<const sh8*>(&As[(wm + fm * 16 + (lane & 15)) * 64 + ki]);
            #pragma unroll
            for (int fn = 0; fn < 4; ++fn)
                bq[fn] = *reinterpret_cast<const sh8*>(&Bs[(wn + fn * 16 + (lane & 15)) * 64 + ki]);
            #pragma unroll
            for (int fm = 0; fm < 4; ++fm)
                #pragma unroll
                for (int fn = 0; fn < 4; ++fn)
                    acc[fm][fn] = __builtin_amdgcn_mfma_f32_16x16x32_bf16(af[fm], bq[fn], acc[fm][fn], 0, 0, 0);
        }
        __syncthreads();
    }

    #pragma unroll
    for (int fm = 0; fm < 4; ++fm)
        #pragma unroll
        for (int r = 0; r < 4; ++r) {
            int row = m0 + wm + fm * 16 + (lane >> 4) * 4 + r;
            #pragma unroll
            for (int fn = 0; fn < 4; ++fn) {
                int col = n0 + wn + fn * 16 + (lane & 15);
                if (Y_F32) Yf[(size_t)row * DIM + col] = acc[fm][fn][r];
                else       Yb[(size_t)row * DIM + col] = bf(acc[fm][fn][r]);
            }
        }
}

// ---------------- Combine: out[t] = sum_k w_k * Y[row(t,k)] ----------------
template<bool Y_F32>
__global__ __launch_bounds__(256) void combine_kernel(
    const float* __restrict__ Yf, const short* __restrict__ Yb,
    const int* __restrict__ cnt, const int* __restrict__ topk_idx,
    const float* __restrict__ topk_w, const int* __restrict__ posmap,
    float* __restrict__ out)
{
    int t = blockIdx.x;
    int d = threadIdx.x * 4;
    int es[TOPK], rows[TOPK];
    #pragma unroll
    for (int k = 0; k < TOPK; ++k) es[k] = topk_idx[t * TOPK + k];
    int p = 0;
    #pragma unroll
    for (int i = 0; i < NEXP; ++i) {
        #pragma unroll
        for (int k = 0; k < TOPK; ++k)
            if (es[k] == i) rows[k] = p + posmap[t * TOPK + k];
        p += ((cnt[i] + 127) >> 7) << 7;
    }
    float4 acc = make_float4(0.f, 0.f, 0.f, 0.f);
    #pragma unroll
    for (int k = 0; k < TOPK; ++k) {
        float w = topk_w[t * TOPK + k];
        if (Y_F32) {
            float4 y = *reinterpret_cast<const float4*>(Yf + (size_t)rows[k] * DIM + d);
            acc.x += w * y.x; acc.y += w * y.y; acc.z += w * y.z; acc.w += w * y.w;
        } else {
            short4 y = *reinterpret_cast<const short4*>(Yb + (size_t)rows[k] * DIM + d);
            acc.x += w * bf2f(y.x); acc.y += w * bf2f(y.y);
            acc.z += w * bf2f(y.z); acc.w += w * bf2f(y.w);
        }
    }
    *reinterpret_cast<float4*>(out + (size_t)t * DIM + d) = acc;
}

// ---------------- launch ----------------
extern "C" void kernel_launch(void* const* d_in, const int* in_sizes, int n_in,
                              void* d_out, int out_size, void* d_ws, size_t ws_size,
                              hipStream_t stream)
{
    const float* X    = (const float*)d_in[0];
    const float* GW   = (const float*)d_in[1];
    const float* GUP  = (const float*)d_in[2];
    const float* DP   = (const float*)d_in[3];
    const float* BIAS = (const float*)d_in[4];
    float* out = (float*)d_out;

    char* ws = (char*)d_ws;
    int*   cnt      = (int*)ws;                       // 128 B
    int*   topk_idx = (int*)(ws + (4u   << 10));      // 64 KB
    float* topk_w   = (float*)(ws + (68u  << 10));    // 64 KB
    int*   posmap   = (int*)(ws + (132u << 10));      // 64 KB
    int*   tlist_c  = (int*)(ws + (196u << 10));      // 512 KB
    int*   tlist_p  = (int*)(ws + (708u << 10));      // 80 KB

    constexpr size_t OFF_H   = 2ull << 20;
    constexpr size_t SZ_ROWS = (size_t)RPAD * IDIM * 2;             // 40 MB
    constexpr size_t OFF_XG  = OFF_H + SZ_ROWS;
    constexpr size_t OFF_WGU = OFF_XG + SZ_ROWS;
    constexpr size_t OFF_WD  = OFF_WGU + GUP_ELEMS * 2;
    constexpr size_t END_ALL = OFF_WD + (ALL_ELEMS - GUP_ELEMS) * 2; // ~287 MB
    constexpr size_t SZ_YF   = (size_t)RPAD * DIM * 4;              // 80 MB

    short* H   = (short*)(ws + OFF_H);
    short* Xg  = (short*)(ws + OFF_XG);
    short* Wgu = (short*)(ws + OFF_WGU);
    short* Wd  = (short*)(ws + OFF_WD);
    float* Yf  = (float*)(ws + END_ALL);
    short* Yb  = Xg;                                  // Xg dead after gemm1

    bool t1   = ws_size >= END_ALL;
    bool t2   = ws_size >= OFF_WGU;
    bool yf32 = ws_size >= END_ALL + SZ_YF;

    (void)hipMemsetAsync(cnt, 0, 128, stream);

    if (t1) front_kernel<true ><<<CONV_BLOCKS + ROUTER_BLOCKS, 256, 0, stream>>>(
        X, GW, BIAS, GUP, DP, Wgu, Wd, topk_idx, topk_w, cnt, tlist_c, posmap);
    else    front_kernel<false><<<ROUTER_BLOCKS, 256, 0, stream>>>(
        X, GW, BIAS, GUP, DP, Wgu, Wd, topk_idx, topk_w, cnt, tlist_c, posmap);

    if (t2) gather_kernel<true ><<<RPAD / 4, 256, 0, stream>>>(X, cnt, tlist_c, Xg, tlist_p);
    else    gather_kernel<false><<<RPAD / 4, 256, 0, stream>>>(X, cnt, tlist_c, Xg, tlist_p);

    int g1 = MAXT * 16;   // 2560, %8==0 for XCD swizzle
    if (t1)      gemm1_kernel<true , true ><<<g1, 256, 0, stream>>>(Xg, X, Wgu, GUP, cnt, tlist_p, H);
    else if (t2) gemm1_kernel<true , false><<<g1, 256, 0, stream>>>(Xg, X, Wgu, GUP, cnt, tlist_p, H);
    else         gemm1_kernel<false, false><<<g1, 256, 0, stream>>>(Xg, X, Wgu, GUP, cnt, tlist_p, H);

    int g2 = MAXT * 8;    // 1280, %8==0
    if (t1) {
        if (yf32) gemm2_kernel<true , true ><<<g2, 256, 0, stream>>>(H, Wd, DP, cnt, Yf, Yb);
        else      gemm2_kernel<true , false><<<g2, 256, 0, stream>>>(H, Wd, DP, cnt, Yf, Yb);
    } else {
        if (yf32) gemm2_kernel<false, true ><<<g2, 256, 0, stream>>>(H, Wd, DP, cnt, Yf, Yb);
        else      gemm2_kernel<false, false><<<g2, 256, 0, stream>>>(H, Wd, DP, cnt, Yf, Yb);
    }

    if (yf32) combine_kernel<true ><<<T_TOK, 256, 0, stream>>>(Yf, Yb, cnt, topk_idx, topk_w, posmap, out);
    else      combine_kernel<false><<<T_TOK, 256, 0, stream>>>(Yf, Yb, cnt, topk_idx, topk_w, posmap, out);
}